// Round 6
// baseline (1147.227 us; speedup 1.0000x reference)
//
#include <hip/hip_runtime.h>

// OnsetLSTM: 2-layer LSTM, B=256, T=512, D=160, H=128, fp32 in/out.
// 256 blocks (1 batch row each) x 1024 threads (16 waves, 4/SIMD — matches
// the 128-VGPR cap the allocator insists on; R2/R4/R5 all spilled trying to
// exceed it, costing ~40-74MB of scratch HBM writes per dispatch).
// Thread = (cell c=tid>>3, K-chunk s=tid&7). Each thread holds all 4 gate
// rows of its cell over K/8: L0 = 4*(12+8) = 80 f16-pair VGPRs, L1 = 64.
// Total live ~115 regs < 128 -> no spill BY CONSTRUCTION.
// Reduce over s: quad_perm xor1, xor2, then row_half_mirror (values are
// quad-uniform after the first two stages, so the 8-lane group completes).
// All VALU; no ds_swizzle; no gate LDS round-trip; 1 barrier/step.
// Layer-0 h-sequence lives in LDS (128KB) and feeds layer 1 directly.

typedef _Float16 half2_t __attribute__((ext_vector_type(2)));

#define TSTEPS 512
#define HID 128

static __device__ __forceinline__ unsigned pack2(float a, float b) {
  half2_t h; h[0] = (_Float16)a; h[1] = (_Float16)b;
  return __builtin_bit_cast(unsigned, h);
}

static __device__ __forceinline__ float dot2f(unsigned a, unsigned b, float c) {
#if __has_builtin(__builtin_amdgcn_fdot2)
  return __builtin_amdgcn_fdot2(__builtin_bit_cast(half2_t, a),
                                __builtin_bit_cast(half2_t, b), c, false);
#else
  half2_t x = __builtin_bit_cast(half2_t, a);
  half2_t y = __builtin_bit_cast(half2_t, b);
  float r = c;
  r = fmaf((float)x[0], (float)y[0], r);
  r = fmaf((float)x[1], (float)y[1], r);
  return r;
#endif
}

static __device__ __forceinline__ float fast_rcp(float x) {
#if __has_builtin(__builtin_amdgcn_rcpf)
  return __builtin_amdgcn_rcpf(x);
#else
  return 1.0f / x;
#endif
}
static __device__ __forceinline__ float fast_exp2(float x) {
#if __has_builtin(__builtin_amdgcn_exp2f)
  return __builtin_amdgcn_exp2f(x);
#else
  return exp2f(x);
#endif
}
// sigm(x) = 1/(1+2^(-x*log2e)); saturates correctly at +-inf
static __device__ __forceinline__ float sigm(float x) {
  return fast_rcp(1.0f + fast_exp2(x * -1.44269504f));
}
static __device__ __forceinline__ float tanh_f(float x) {
  // 1 - 2/(exp2(2x*log2e)+1); saturates correctly both ways
  float e = fast_exp2(x * 2.885390082f);
  return 1.0f - 2.0f * fast_rcp(e + 1.0f);
}

// DPP butterfly-add stage. CTRL: 0xB1 quad xor1, 0x4E quad xor2,
// 0x141 row_half_mirror (crosses quads within each 8-lane group).
template <int CTRL>
static __device__ __forceinline__ float qp_add(float v) {
  int iv = __builtin_bit_cast(int, v);
  int t = __builtin_amdgcn_update_dpp(iv, iv, CTRL, 0xF, 0xF, true);
  return v + __builtin_bit_cast(float, t);
}
// full 8-lane-group reduction
static __device__ __forceinline__ float red8(float v) {
  v = qp_add<0xB1>(v);
  v = qp_add<0x4E>(v);
  v = qp_add<0x141>(v);
  return v;
}

__global__ __attribute__((amdgpu_flat_work_group_size(1024, 1024)))
__attribute__((amdgpu_waves_per_eu(4, 4)))
void lstm_fused(
    const float* __restrict__ x,     // [256,512,160]
    const float* __restrict__ h0,    // [2,256,128]
    const float* __restrict__ c0,    // [2,256,128]
    const float* __restrict__ Wih0,  // [512,160]
    const float* __restrict__ Whh0,  // [512,128]
    const float* __restrict__ bih0, const float* __restrict__ bhh0,
    const float* __restrict__ Wih1,  // [512,128]
    const float* __restrict__ Whh1,  // [512,128]
    const float* __restrict__ bih1, const float* __restrict__ bhh1,
    float* __restrict__ out)         // [256,128]
{
  const int b   = blockIdx.x;
  const int tid = threadIdx.x;
  const int c   = tid >> 3;  // cell column 0..127
  const int s   = tid & 7;   // K-chunk 0..7

  __shared__ unsigned h1s[TSTEPS][64];  // 128 KB: layer-0 h_t as f16 pairs
  __shared__ unsigned xbuf[2][96];      // x_t f16 pairs, padded 80->96, dbuf
  __shared__ unsigned h0buf[64];        // layer-0 initial h
  __shared__ unsigned hbuf[2][64];      // layer-1 recurrent h, dbuf

  // ======================= Phase 0: layer 0 (K = 160 + 128) ==============
  {
    // per thread: 4 gate rows, pairs [12s,12s+12) of padded-x and [8s,8s+8) of h
    unsigned wx[4][12], wh[4][8];
    float bias[4];
#pragma unroll
    for (int g = 0; g < 4; ++g) {
      const int r = g * HID + c;
#pragma unroll
      for (int j = 0; j < 12; ++j) {
        int p = 12 * s + j;
        float a0 = (2 * p < 160) ? Wih0[r * 160 + 2 * p] : 0.f;
        float a1 = (2 * p + 1 < 160) ? Wih0[r * 160 + 2 * p + 1] : 0.f;
        wx[g][j] = pack2(a0, a1);
      }
#pragma unroll
      for (int j = 0; j < 8; ++j) {
        int p = 8 * s + j;
        wh[g][j] = pack2(Whh0[r * HID + 2 * p], Whh0[r * HID + 2 * p + 1]);
      }
      bias[g] = bih0[r] + bhh0[r];
    }

    float cst = c0[b * HID + c];  // replicated across the 8-lane group

    if (tid < 64) h0buf[tid] = pack2(h0[b * HID + 2 * tid], h0[b * HID + 2 * tid + 1]);
    if (tid < 80) {
      float2 v = *(const float2*)&x[((size_t)b * TSTEPS + 0) * 160 + 2 * tid];
      xbuf[0][tid] = pack2(v.x, v.y);
    }
    if (tid >= 80 && tid < 96) { xbuf[0][tid] = 0u; xbuf[1][tid] = 0u; }
    float2 xA = make_float2(0.f, 0.f);  // x_{t+1} in regs
    if (tid < 80) xA = *(const float2*)&x[((size_t)b * TSTEPS + 1) * 160 + 2 * tid];
    __syncthreads();

#pragma unroll 1
    for (int t = 0; t < TSTEPS; ++t) {
      // issue x_{t+2} load now; consumed next iteration (latency hidden)
      float2 xB = xA;
      if (tid < 80) {
        int tn = (t + 2 < TSTEPS) ? t + 2 : TSTEPS - 1;
        xB = *(const float2*)&x[((size_t)b * TSTEPS + tn) * 160 + 2 * tid];
      }

      const uint4* xs = (const uint4*)&xbuf[t & 1][12 * s];  // 3 x uint4
      const uint4* hs = (t == 0) ? (const uint4*)&h0buf[8 * s]
                                 : (const uint4*)&h1s[t - 1][8 * s];  // 2 x uint4
      float ai = 0.f, af = 0.f, ag = 0.f, ao = 0.f;
#pragma unroll
      for (int k = 0; k < 3; ++k) {
        uint4 v = xs[k];
        ai = dot2f(v.x, wx[0][4 * k + 0], ai); ai = dot2f(v.y, wx[0][4 * k + 1], ai);
        ai = dot2f(v.z, wx[0][4 * k + 2], ai); ai = dot2f(v.w, wx[0][4 * k + 3], ai);
        af = dot2f(v.x, wx[1][4 * k + 0], af); af = dot2f(v.y, wx[1][4 * k + 1], af);
        af = dot2f(v.z, wx[1][4 * k + 2], af); af = dot2f(v.w, wx[1][4 * k + 3], af);
        ag = dot2f(v.x, wx[2][4 * k + 0], ag); ag = dot2f(v.y, wx[2][4 * k + 1], ag);
        ag = dot2f(v.z, wx[2][4 * k + 2], ag); ag = dot2f(v.w, wx[2][4 * k + 3], ag);
        ao = dot2f(v.x, wx[3][4 * k + 0], ao); ao = dot2f(v.y, wx[3][4 * k + 1], ao);
        ao = dot2f(v.z, wx[3][4 * k + 2], ao); ao = dot2f(v.w, wx[3][4 * k + 3], ao);
      }
#pragma unroll
      for (int k = 0; k < 2; ++k) {
        uint4 v = hs[k];
        ai = dot2f(v.x, wh[0][4 * k + 0], ai); ai = dot2f(v.y, wh[0][4 * k + 1], ai);
        ai = dot2f(v.z, wh[0][4 * k + 2], ai); ai = dot2f(v.w, wh[0][4 * k + 3], ai);
        af = dot2f(v.x, wh[1][4 * k + 0], af); af = dot2f(v.y, wh[1][4 * k + 1], af);
        af = dot2f(v.z, wh[1][4 * k + 2], af); af = dot2f(v.w, wh[1][4 * k + 3], af);
        ag = dot2f(v.x, wh[2][4 * k + 0], ag); ag = dot2f(v.y, wh[2][4 * k + 1], ag);
        ag = dot2f(v.z, wh[2][4 * k + 2], ag); ag = dot2f(v.w, wh[2][4 * k + 3], ag);
        ao = dot2f(v.x, wh[3][4 * k + 0], ao); ao = dot2f(v.y, wh[3][4 * k + 1], ao);
        ao = dot2f(v.z, wh[3][4 * k + 2], ao); ao = dot2f(v.w, wh[3][4 * k + 3], ao);
      }
      // 8-lane butterfly: every lane gets all four full K-sums
      ai = red8(ai); af = red8(af); ag = red8(ag); ao = red8(ao);

      float iv = sigm(ai + bias[0]);
      float fv = sigm(af + bias[1]);
      float gv = tanh_f(ag + bias[2]);
      float ov = sigm(ao + bias[3]);
      cst = fv * cst + iv * gv;
      float h = ov * tanh_f(cst);

      if (s == 0) ((_Float16*)h1s)[t * HID + c] = (_Float16)h;
      if (tid < 80) xbuf[(t + 1) & 1][tid] = pack2(xA.x, xA.y);
      __syncthreads();
      xA = xB;
    }
  }

  // ======================= Phase 1: layer 1 (K = 128 + 128) ==============
  {
    unsigned w1x[4][8], w1h[4][8];
    float bias[4];
#pragma unroll
    for (int g = 0; g < 4; ++g) {
      const int r = g * HID + c;
#pragma unroll
      for (int j = 0; j < 8; ++j) {
        int p = 8 * s + j;
        w1x[g][j] = pack2(Wih1[r * HID + 2 * p], Wih1[r * HID + 2 * p + 1]);
        w1h[g][j] = pack2(Whh1[r * HID + 2 * p], Whh1[r * HID + 2 * p + 1]);
      }
      bias[g] = bih1[r] + bhh1[r];
    }

    const float* h0b = h0 + 256 * HID;
    const float* c0b = c0 + 256 * HID;
    float cst = c0b[b * HID + c];
    if (tid < 64) hbuf[0][tid] = pack2(h0b[b * HID + 2 * tid], h0b[b * HID + 2 * tid + 1]);
    __syncthreads();

    float hlast = 0.f;
#pragma unroll 1
    for (int t = 0; t < TSTEPS; ++t) {
      const uint4* xs = (const uint4*)&h1s[t][8 * s];        // layer-0 h_t
      const uint4* hs = (const uint4*)&hbuf[t & 1][8 * s];   // own h_{t-1}
      float ai = 0.f, af = 0.f, ag = 0.f, ao = 0.f;
#pragma unroll
      for (int k = 0; k < 2; ++k) {
        uint4 v = xs[k];
        ai = dot2f(v.x, w1x[0][4 * k + 0], ai); ai = dot2f(v.y, w1x[0][4 * k + 1], ai);
        ai = dot2f(v.z, w1x[0][4 * k + 2], ai); ai = dot2f(v.w, w1x[0][4 * k + 3], ai);
        af = dot2f(v.x, w1x[1][4 * k + 0], af); af = dot2f(v.y, w1x[1][4 * k + 1], af);
        af = dot2f(v.z, w1x[1][4 * k + 2], af); af = dot2f(v.w, w1x[1][4 * k + 3], af);
        ag = dot2f(v.x, w1x[2][4 * k + 0], ag); ag = dot2f(v.y, w1x[2][4 * k + 1], ag);
        ag = dot2f(v.z, w1x[2][4 * k + 2], ag); ag = dot2f(v.w, w1x[2][4 * k + 3], ag);
        ao = dot2f(v.x, w1x[3][4 * k + 0], ao); ao = dot2f(v.y, w1x[3][4 * k + 1], ao);
        ao = dot2f(v.z, w1x[3][4 * k + 2], ao); ao = dot2f(v.w, w1x[3][4 * k + 3], ao);
      }
#pragma unroll
      for (int k = 0; k < 2; ++k) {
        uint4 v = hs[k];
        ai = dot2f(v.x, w1h[0][4 * k + 0], ai); ai = dot2f(v.y, w1h[0][4 * k + 1], ai);
        ai = dot2f(v.z, w1h[0][4 * k + 2], ai); ai = dot2f(v.w, w1h[0][4 * k + 3], ai);
        af = dot2f(v.x, w1h[1][4 * k + 0], af); af = dot2f(v.y, w1h[1][4 * k + 1], af);
        af = dot2f(v.z, w1h[1][4 * k + 2], af); af = dot2f(v.w, w1h[1][4 * k + 3], af);
        ag = dot2f(v.x, w1h[2][4 * k + 0], ag); ag = dot2f(v.y, w1h[2][4 * k + 1], ag);
        ag = dot2f(v.z, w1h[2][4 * k + 2], ag); ag = dot2f(v.w, w1h[2][4 * k + 3], ag);
        ao = dot2f(v.x, w1h[3][4 * k + 0], ao); ao = dot2f(v.y, w1h[3][4 * k + 1], ao);
        ao = dot2f(v.z, w1h[3][4 * k + 2], ao); ao = dot2f(v.w, w1h[3][4 * k + 3], ao);
      }
      ai = red8(ai); af = red8(af); ag = red8(ag); ao = red8(ao);

      float iv = sigm(ai + bias[0]);
      float fv = sigm(af + bias[1]);
      float gv = tanh_f(ag + bias[2]);
      float ov = sigm(ao + bias[3]);
      cst = fv * cst + iv * gv;
      float h = ov * tanh_f(cst);
      hlast = h;

      if (s == 0) ((_Float16*)&hbuf[(t + 1) & 1][0])[c] = (_Float16)h;
      __syncthreads();
    }
    if (s == 0) out[b * HID + c] = hlast;
  }
}

extern "C" void kernel_launch(void* const* d_in, const int* in_sizes, int n_in,
                              void* d_out, int out_size, void* d_ws,
                              size_t ws_size, hipStream_t stream) {
  const float* x    = (const float*)d_in[0];
  const float* h0   = (const float*)d_in[1];
  const float* c0   = (const float*)d_in[2];
  const float* Wih0 = (const float*)d_in[3];
  const float* Whh0 = (const float*)d_in[4];
  const float* bih0 = (const float*)d_in[5];
  const float* bhh0 = (const float*)d_in[6];
  const float* Wih1 = (const float*)d_in[7];
  const float* Whh1 = (const float*)d_in[8];
  const float* bih1 = (const float*)d_in[9];
  const float* bhh1 = (const float*)d_in[10];

  lstm_fused<<<256, 1024, 0, stream>>>(x, h0, c0, Wih0, Whh0, bih0, bhh0,
                                       Wih1, Whh1, bih1, bhh1, (float*)d_out);
}

// Round 7
// 871.865 us; speedup vs baseline: 1.3158x; 1.3158x over previous
//
#include <hip/hip_runtime.h>

// OnsetLSTM: 2-layer LSTM, B=256, T=512, D=160, H=128, fp32 in/out.
// 256 blocks (1 batch row each) x 512 threads (8 waves, 2/SIMD).
// Thread = (cell c=tid>>2, K-chunk s=tid&3). Each thread holds ALL FOUR gate
// rows (i,f,g,o) of its cell over K/4 as 144 f16-pair VGPRs.
//
// Register story (R2/R4/R5/R6 evidence): gfx950 has a unified VGPR/AGPR file;
// the allocator takes the unified budget for min-waves-per-EU and splits it
// 50/50 arch/AGPR. (2,2)->128 arch, (4,4)->64 arch; the deficit spilled to
// SCRATCH (39-78MB WRITE_SIZE = the whole slowdown). waves_per_eu(1,1) makes
// the unified budget 512 -> arch cap 256 >= the ~175 this kernel needs.
// Actual occupancy is launch-determined (1 block/CU, 2 waves/SIMD) and still
// fits: 2 waves x 256 = 512-reg file.
//
// Per step: 9 broadcast ds_read_b128 -> 144 v_dot2 -> 2-DPP quad butterfly
// per gate -> cell update replicated per quad -> 1 barrier. No gate LDS
// round-trip. Layer-0 h-sequence lives in LDS (128KB) and feeds layer 1.

typedef _Float16 half2_t __attribute__((ext_vector_type(2)));

#define TSTEPS 512
#define HID 128

static __device__ __forceinline__ unsigned pack2(float a, float b) {
  half2_t h; h[0] = (_Float16)a; h[1] = (_Float16)b;
  return __builtin_bit_cast(unsigned, h);
}

static __device__ __forceinline__ float dot2f(unsigned a, unsigned b, float c) {
#if __has_builtin(__builtin_amdgcn_fdot2)
  return __builtin_amdgcn_fdot2(__builtin_bit_cast(half2_t, a),
                                __builtin_bit_cast(half2_t, b), c, false);
#else
  half2_t x = __builtin_bit_cast(half2_t, a);
  half2_t y = __builtin_bit_cast(half2_t, b);
  float r = c;
  r = fmaf((float)x[0], (float)y[0], r);
  r = fmaf((float)x[1], (float)y[1], r);
  return r;
#endif
}

static __device__ __forceinline__ float fast_rcp(float x) {
#if __has_builtin(__builtin_amdgcn_rcpf)
  return __builtin_amdgcn_rcpf(x);
#else
  return 1.0f / x;
#endif
}
static __device__ __forceinline__ float fast_exp2(float x) {
#if __has_builtin(__builtin_amdgcn_exp2f)
  return __builtin_amdgcn_exp2f(x);
#else
  return exp2f(x);
#endif
}
// sigm(x) = 1/(1+2^(-x*log2e)); saturates correctly at +-inf
static __device__ __forceinline__ float sigm(float x) {
  return fast_rcp(1.0f + fast_exp2(x * -1.44269504f));
}
static __device__ __forceinline__ float tanh_f(float x) {
  // 1 - 2/(exp2(2x*log2e)+1); saturates correctly both ways
  float e = fast_exp2(x * 2.885390082f);
  return 1.0f - 2.0f * fast_rcp(e + 1.0f);
}

// butterfly add over quad (aligned groups of 4): CTRL 0xB1=xor1, 0x4E=xor2
template <int CTRL>
static __device__ __forceinline__ float qp_add(float v) {
  int iv = __builtin_bit_cast(int, v);
  int t = __builtin_amdgcn_update_dpp(iv, iv, CTRL, 0xF, 0xF, true);
  return v + __builtin_bit_cast(float, t);
}

__global__ __launch_bounds__(512) __attribute__((amdgpu_waves_per_eu(1, 1)))
void lstm_fused(
    const float* __restrict__ x,     // [256,512,160]
    const float* __restrict__ h0,    // [2,256,128]
    const float* __restrict__ c0,    // [2,256,128]
    const float* __restrict__ Wih0,  // [512,160]
    const float* __restrict__ Whh0,  // [512,128]
    const float* __restrict__ bih0, const float* __restrict__ bhh0,
    const float* __restrict__ Wih1,  // [512,128]
    const float* __restrict__ Whh1,  // [512,128]
    const float* __restrict__ bih1, const float* __restrict__ bhh1,
    float* __restrict__ out)         // [256,128]
{
  const int b   = blockIdx.x;
  const int tid = threadIdx.x;
  const int c   = tid >> 2;  // cell column 0..127
  const int s   = tid & 3;   // K-chunk 0..3

  __shared__ unsigned h1s[TSTEPS][64];  // 128 KB: layer-0 h_t as f16 pairs
  __shared__ unsigned xbuf[2][80];      // x_t as f16 pairs, double-buffered
  __shared__ unsigned h0buf[64];        // layer-0 initial h
  __shared__ unsigned hbuf[2][64];      // layer-1 recurrent h, double-buffered

  // ======================= Phase 0: layer 0 (K = 160 + 128) ==============
  {
    // rows r = g*128 + c for g in {i,f,g,o}; K-chunk s.
    // x-part: 80 pairs total -> 20/thread (5 uint4); h-part: 64 -> 16 (4 uint4).
    unsigned wx[4][20], wh[4][16];
    float bias[4];
#pragma unroll
    for (int g = 0; g < 4; ++g) {
      const int r = g * HID + c;
#pragma unroll
      for (int j = 0; j < 20; ++j) {
        int p = 20 * s + j;
        wx[g][j] = pack2(Wih0[r * 160 + 2 * p], Wih0[r * 160 + 2 * p + 1]);
      }
#pragma unroll
      for (int j = 0; j < 16; ++j) {
        int p = 16 * s + j;
        wh[g][j] = pack2(Whh0[r * HID + 2 * p], Whh0[r * HID + 2 * p + 1]);
      }
      bias[g] = bih0[r] + bhh0[r];
    }

    float cst = c0[b * HID + c];  // replicated across the quad

    if (tid < 64) h0buf[tid] = pack2(h0[b * HID + 2 * tid], h0[b * HID + 2 * tid + 1]);
    if (tid < 80) {
      float2 v = *(const float2*)&x[((size_t)b * TSTEPS + 0) * 160 + 2 * tid];
      xbuf[0][tid] = pack2(v.x, v.y);
    }
    float2 xA = make_float2(0.f, 0.f);  // x_{t+1} in regs
    if (tid < 80) xA = *(const float2*)&x[((size_t)b * TSTEPS + 1) * 160 + 2 * tid];
    __syncthreads();

#pragma unroll 1
    for (int t = 0; t < TSTEPS; ++t) {
      // issue x_{t+2} load now; consumed next iteration (latency hidden)
      float2 xB = xA;
      if (tid < 80) {
        int tn = (t + 2 < TSTEPS) ? t + 2 : TSTEPS - 1;
        xB = *(const float2*)&x[((size_t)b * TSTEPS + tn) * 160 + 2 * tid];
      }

      const uint4* xs = (const uint4*)&xbuf[t & 1][20 * s];
      const uint4* hs = (t == 0) ? (const uint4*)&h0buf[16 * s]
                                 : (const uint4*)&h1s[t - 1][16 * s];
      float ai = 0.f, af = 0.f, ag = 0.f, ao = 0.f;
#pragma unroll
      for (int k = 0; k < 5; ++k) {
        uint4 v = xs[k];
        ai = dot2f(v.x, wx[0][4 * k + 0], ai); ai = dot2f(v.y, wx[0][4 * k + 1], ai);
        ai = dot2f(v.z, wx[0][4 * k + 2], ai); ai = dot2f(v.w, wx[0][4 * k + 3], ai);
        af = dot2f(v.x, wx[1][4 * k + 0], af); af = dot2f(v.y, wx[1][4 * k + 1], af);
        af = dot2f(v.z, wx[1][4 * k + 2], af); af = dot2f(v.w, wx[1][4 * k + 3], af);
        ag = dot2f(v.x, wx[2][4 * k + 0], ag); ag = dot2f(v.y, wx[2][4 * k + 1], ag);
        ag = dot2f(v.z, wx[2][4 * k + 2], ag); ag = dot2f(v.w, wx[2][4 * k + 3], ag);
        ao = dot2f(v.x, wx[3][4 * k + 0], ao); ao = dot2f(v.y, wx[3][4 * k + 1], ao);
        ao = dot2f(v.z, wx[3][4 * k + 2], ao); ao = dot2f(v.w, wx[3][4 * k + 3], ao);
      }
#pragma unroll
      for (int k = 0; k < 4; ++k) {
        uint4 v = hs[k];
        ai = dot2f(v.x, wh[0][4 * k + 0], ai); ai = dot2f(v.y, wh[0][4 * k + 1], ai);
        ai = dot2f(v.z, wh[0][4 * k + 2], ai); ai = dot2f(v.w, wh[0][4 * k + 3], ai);
        af = dot2f(v.x, wh[1][4 * k + 0], af); af = dot2f(v.y, wh[1][4 * k + 1], af);
        af = dot2f(v.z, wh[1][4 * k + 2], af); af = dot2f(v.w, wh[1][4 * k + 3], af);
        ag = dot2f(v.x, wh[2][4 * k + 0], ag); ag = dot2f(v.y, wh[2][4 * k + 1], ag);
        ag = dot2f(v.z, wh[2][4 * k + 2], ag); ag = dot2f(v.w, wh[2][4 * k + 3], ag);
        ao = dot2f(v.x, wh[3][4 * k + 0], ao); ao = dot2f(v.y, wh[3][4 * k + 1], ao);
        ao = dot2f(v.z, wh[3][4 * k + 2], ao); ao = dot2f(v.w, wh[3][4 * k + 3], ao);
      }
      // quad butterfly: every lane of the quad gets all four full K-sums
      ai = qp_add<0xB1>(ai); ai = qp_add<0x4E>(ai);
      af = qp_add<0xB1>(af); af = qp_add<0x4E>(af);
      ag = qp_add<0xB1>(ag); ag = qp_add<0x4E>(ag);
      ao = qp_add<0xB1>(ao); ao = qp_add<0x4E>(ao);

      float iv = sigm(ai + bias[0]);
      float fv = sigm(af + bias[1]);
      float gv = tanh_f(ag + bias[2]);
      float ov = sigm(ao + bias[3]);
      cst = fv * cst + iv * gv;
      float h = ov * tanh_f(cst);

      if (s == 0) ((_Float16*)h1s)[t * HID + c] = (_Float16)h;
      if (tid < 80) xbuf[(t + 1) & 1][tid] = pack2(xA.x, xA.y);
      __syncthreads();
      xA = xB;
    }
  }

  // ======================= Phase 1: layer 1 (K = 128 + 128) ==============
  {
    unsigned w1x[4][16], w1h[4][16];
    float bias[4];
#pragma unroll
    for (int g = 0; g < 4; ++g) {
      const int r = g * HID + c;
#pragma unroll
      for (int j = 0; j < 16; ++j) {
        int p = 16 * s + j;
        w1x[g][j] = pack2(Wih1[r * HID + 2 * p], Wih1[r * HID + 2 * p + 1]);
        w1h[g][j] = pack2(Whh1[r * HID + 2 * p], Whh1[r * HID + 2 * p + 1]);
      }
      bias[g] = bih1[r] + bhh1[r];
    }

    const float* h0b = h0 + 256 * HID;
    const float* c0b = c0 + 256 * HID;
    float cst = c0b[b * HID + c];
    if (tid < 64) hbuf[0][tid] = pack2(h0b[b * HID + 2 * tid], h0b[b * HID + 2 * tid + 1]);
    __syncthreads();

    float hlast = 0.f;
#pragma unroll 1
    for (int t = 0; t < TSTEPS; ++t) {
      const uint4* xs = (const uint4*)&h1s[t][16 * s];       // layer-0 h_t
      const uint4* hs = (const uint4*)&hbuf[t & 1][16 * s];  // own h_{t-1}
      float ai = 0.f, af = 0.f, ag = 0.f, ao = 0.f;
#pragma unroll
      for (int k = 0; k < 4; ++k) {
        uint4 v = xs[k];
        ai = dot2f(v.x, w1x[0][4 * k + 0], ai); ai = dot2f(v.y, w1x[0][4 * k + 1], ai);
        ai = dot2f(v.z, w1x[0][4 * k + 2], ai); ai = dot2f(v.w, w1x[0][4 * k + 3], ai);
        af = dot2f(v.x, w1x[1][4 * k + 0], af); af = dot2f(v.y, w1x[1][4 * k + 1], af);
        af = dot2f(v.z, w1x[1][4 * k + 2], af); af = dot2f(v.w, w1x[1][4 * k + 3], af);
        ag = dot2f(v.x, w1x[2][4 * k + 0], ag); ag = dot2f(v.y, w1x[2][4 * k + 1], ag);
        ag = dot2f(v.z, w1x[2][4 * k + 2], ag); ag = dot2f(v.w, w1x[2][4 * k + 3], ag);
        ao = dot2f(v.x, w1x[3][4 * k + 0], ao); ao = dot2f(v.y, w1x[3][4 * k + 1], ao);
        ao = dot2f(v.z, w1x[3][4 * k + 2], ao); ao = dot2f(v.w, w1x[3][4 * k + 3], ao);
      }
#pragma unroll
      for (int k = 0; k < 4; ++k) {
        uint4 v = hs[k];
        ai = dot2f(v.x, w1h[0][4 * k + 0], ai); ai = dot2f(v.y, w1h[0][4 * k + 1], ai);
        ai = dot2f(v.z, w1h[0][4 * k + 2], ai); ai = dot2f(v.w, w1h[0][4 * k + 3], ai);
        af = dot2f(v.x, w1h[1][4 * k + 0], af); af = dot2f(v.y, w1h[1][4 * k + 1], af);
        af = dot2f(v.z, w1h[1][4 * k + 2], af); af = dot2f(v.w, w1h[1][4 * k + 3], af);
        ag = dot2f(v.x, w1h[2][4 * k + 0], ag); ag = dot2f(v.y, w1h[2][4 * k + 1], ag);
        ag = dot2f(v.z, w1h[2][4 * k + 2], ag); ag = dot2f(v.w, w1h[2][4 * k + 3], ag);
        ao = dot2f(v.x, w1h[3][4 * k + 0], ao); ao = dot2f(v.y, w1h[3][4 * k + 1], ao);
        ao = dot2f(v.z, w1h[3][4 * k + 2], ao); ao = dot2f(v.w, w1h[3][4 * k + 3], ao);
      }
      ai = qp_add<0xB1>(ai); ai = qp_add<0x4E>(ai);
      af = qp_add<0xB1>(af); af = qp_add<0x4E>(af);
      ag = qp_add<0xB1>(ag); ag = qp_add<0x4E>(ag);
      ao = qp_add<0xB1>(ao); ao = qp_add<0x4E>(ao);

      float iv = sigm(ai + bias[0]);
      float fv = sigm(af + bias[1]);
      float gv = tanh_f(ag + bias[2]);
      float ov = sigm(ao + bias[3]);
      cst = fv * cst + iv * gv;
      float h = ov * tanh_f(cst);
      hlast = h;

      if (s == 0) ((_Float16*)&hbuf[(t + 1) & 1][0])[c] = (_Float16)h;
      __syncthreads();
    }
    if (s == 0) out[b * HID + c] = hlast;
  }
}

extern "C" void kernel_launch(void* const* d_in, const int* in_sizes, int n_in,
                              void* d_out, int out_size, void* d_ws,
                              size_t ws_size, hipStream_t stream) {
  const float* x    = (const float*)d_in[0];
  const float* h0   = (const float*)d_in[1];
  const float* c0   = (const float*)d_in[2];
  const float* Wih0 = (const float*)d_in[3];
  const float* Whh0 = (const float*)d_in[4];
  const float* bih0 = (const float*)d_in[5];
  const float* bhh0 = (const float*)d_in[6];
  const float* Wih1 = (const float*)d_in[7];
  const float* Whh1 = (const float*)d_in[8];
  const float* bih1 = (const float*)d_in[9];
  const float* bhh1 = (const float*)d_in[10];

  lstm_fused<<<256, 512, 0, stream>>>(x, h0, c0, Wih0, Whh0, bih0, bhh0,
                                      Wih1, Whh1, bih1, bhh1, (float*)d_out);
}